// Round 2
// baseline (884.430 us; speedup 1.0000x reference)
//
#include <hip/hip_runtime.h>
#include <hip/hip_bf16.h>
#include <stdint.h>

#define BATCH 8
#define NPTS  65536
#define CFEAT 256
#define K1    259     // 3 + 256
#define CH    128
#define NS    1024
#define EPSF  1e-5f

// ---------------------------------------------------------------------------
// 1. Selection: per batch, first NS masked indices in ascending order (fill 0)
// ---------------------------------------------------------------------------
__global__ __launch_bounds__(1024) void k_select(const float* __restrict__ xyz,
                                                 int* __restrict__ inds,
                                                 float* __restrict__ center) {
  int b = blockIdx.x;
  int tid = threadIdx.x;
  int lane = tid & 63, wid = tid >> 6;
  const float* xb = xyz + (size_t)b * NPTS * 3;
  float cx = xb[0], cy = xb[1], cz = xb[2];
  if (tid < 3) center[b * 3 + tid] = xb[tid];

  __shared__ int wcnt[16];
  int total = 0;
  int* ib = inds + b * NS;

  for (int base = 0; base < NPTS; base += 1024) {
    int i = base + tid;
    float dx = xb[(size_t)i * 3 + 0] - cx;
    float dy = xb[(size_t)i * 3 + 1] - cy;
    float dz = xb[(size_t)i * 3 + 2] - cz;
    float d2 = dx * dx + dy * dy + dz * dz;
    bool pred = d2 < 1.0f;
    unsigned long long bal = __ballot(pred);
    if (lane == 0) wcnt[wid] = (int)__popcll(bal);
    __syncthreads();
    int woff = 0, itot = 0;
#pragma unroll
    for (int w = 0; w < 16; ++w) {
      int c = wcnt[w];
      if (w < wid) woff += c;
      itot += c;
    }
    int pos = total + woff + (int)__popcll(bal & ((1ull << lane) - 1ull));
    if (pred && pos < NS) ib[pos] = i;
    total += itot;
    __syncthreads();
    if (total >= NS) break;
  }
  // pad with index 0 (== order[:,0], since point 0 always satisfies d2=0<1)
  for (int j = total + tid; j < NS; j += 1024) ib[j] = 0;
}

// ---------------------------------------------------------------------------
// 2. Gather: g[b][c][n]  (c<3: centered xyz^T, else features)   fp32
// ---------------------------------------------------------------------------
__global__ __launch_bounds__(256) void k_gather(const float* __restrict__ xyz,
                                                const float* __restrict__ feat,
                                                const int* __restrict__ inds,
                                                const float* __restrict__ center,
                                                float* __restrict__ g) {
  int bc = blockIdx.x;
  int b = bc / K1, c = bc % K1;
  const int* ib = inds + b * NS;
  float* gout = g + ((size_t)b * K1 + c) * NS;
  if (c < 3) {
    float cen = center[b * 3 + c];
    for (int n = threadIdx.x; n < NS; n += 256) {
      int id = ib[n];
      gout[n] = xyz[((size_t)b * NPTS + id) * 3 + c] - cen;  // RADIUS=1
    }
  } else {
    const float* fr = feat + ((size_t)b * CFEAT + (c - 3)) * NPTS;
    for (int n = threadIdx.x; n < NS; n += 256) {
      gout[n] = fr[ib[n]];
    }
  }
}

// ---------------------------------------------------------------------------
// 3. GEMM layer 1: y[b][o][n] = sum_c W[o][c]*g[b][c][n] + bias[o]   (K=259)
//    block: 128 rows x 64 cols, 256 threads, K chunks of 32
// ---------------------------------------------------------------------------
__global__ __launch_bounds__(256) void k_gemm1(const float* __restrict__ g,
                                               const float* __restrict__ W,
                                               const float* __restrict__ bias,
                                               float* __restrict__ y) {
  __shared__ float Ws[128 * 32];
  __shared__ float Xs[32 * 64];
  int b = blockIdx.y;
  int n0 = blockIdx.x * 64;
  int tid = threadIdx.x;
  int tx = tid & 15, ty = tid >> 4;
  float acc[8][4];
#pragma unroll
  for (int r = 0; r < 8; ++r)
#pragma unroll
    for (int j = 0; j < 4; ++j) acc[r][j] = 0.f;

  const float* xb = g + (size_t)b * K1 * NS;
  for (int k0 = 0; k0 < K1; k0 += 32) {
    for (int e = tid; e < 128 * 32; e += 256) {
      int o = e >> 5, kk = e & 31;
      int k = k0 + kk;
      Ws[e] = (k < K1) ? W[o * K1 + k] : 0.f;
    }
    for (int e = tid; e < 32 * 64; e += 256) {
      int kk = e >> 6, j = e & 63;
      int k = k0 + kk;
      Xs[e] = (k < K1) ? xb[(size_t)k * NS + n0 + j] : 0.f;
    }
    __syncthreads();
#pragma unroll
    for (int kk = 0; kk < 32; ++kk) {
      float4 xv = *(const float4*)&Xs[kk * 64 + tx * 4];
#pragma unroll
      for (int r = 0; r < 8; ++r) {
        float a = Ws[(ty * 8 + r) * 32 + kk];
        acc[r][0] += a * xv.x;
        acc[r][1] += a * xv.y;
        acc[r][2] += a * xv.z;
        acc[r][3] += a * xv.w;
      }
    }
    __syncthreads();
  }
#pragma unroll
  for (int r = 0; r < 8; ++r) {
    int o = ty * 8 + r;
    float bs = bias[o];
    float4 v = make_float4(acc[r][0] + bs, acc[r][1] + bs, acc[r][2] + bs, acc[r][3] + bs);
    *(float4*)&y[((size_t)b * CH + o) * NS + n0 + tx * 4] = v;
  }
}

// ---------------------------------------------------------------------------
// 3b. GEMM layers 2/3 (K=128), BN+ReLU of previous layer fused into X load
// ---------------------------------------------------------------------------
__global__ __launch_bounds__(256) void k_gemm23(const float* __restrict__ x,
                                                const float* __restrict__ scale,
                                                const float* __restrict__ shift,
                                                const float* __restrict__ W,
                                                const float* __restrict__ bias,
                                                float* __restrict__ y) {
  __shared__ float Ws[128 * 32];
  __shared__ float Xs[32 * 64];
  int b = blockIdx.y;
  int n0 = blockIdx.x * 64;
  int tid = threadIdx.x;
  int tx = tid & 15, ty = tid >> 4;
  float acc[8][4];
#pragma unroll
  for (int r = 0; r < 8; ++r)
#pragma unroll
    for (int j = 0; j < 4; ++j) acc[r][j] = 0.f;

  for (int k0 = 0; k0 < 128; k0 += 32) {
    for (int e = tid; e < 128 * 32; e += 256) {
      int o = e >> 5, kk = e & 31;
      Ws[e] = W[o * 128 + k0 + kk];
    }
    for (int e = tid; e < 32 * 64; e += 256) {
      int kk = e >> 6, j = e & 63;
      int k = k0 + kk;
      float v = x[((size_t)b * CH + k) * NS + n0 + j];
      Xs[e] = fmaxf(scale[k] * v + shift[k], 0.f);  // BN + ReLU of prev layer
    }
    __syncthreads();
#pragma unroll
    for (int kk = 0; kk < 32; ++kk) {
      float4 xv = *(const float4*)&Xs[kk * 64 + tx * 4];
#pragma unroll
      for (int r = 0; r < 8; ++r) {
        float a = Ws[(ty * 8 + r) * 32 + kk];
        acc[r][0] += a * xv.x;
        acc[r][1] += a * xv.y;
        acc[r][2] += a * xv.z;
        acc[r][3] += a * xv.w;
      }
    }
    __syncthreads();
  }
#pragma unroll
  for (int r = 0; r < 8; ++r) {
    int o = ty * 8 + r;
    float bs = bias[o];
    float4 v = make_float4(acc[r][0] + bs, acc[r][1] + bs, acc[r][2] + bs, acc[r][3] + bs);
    *(float4*)&y[((size_t)b * CH + o) * NS + n0 + tx * 4] = v;
  }
}

// ---------------------------------------------------------------------------
// 4. BN stats: per channel c over (B, NS) -> scale/shift
// ---------------------------------------------------------------------------
__global__ __launch_bounds__(256) void k_stats(const float* __restrict__ y,
                                               const float* __restrict__ gamma,
                                               const float* __restrict__ beta,
                                               float* __restrict__ scale,
                                               float* __restrict__ shift) {
  int c = blockIdx.x;
  int tid = threadIdx.x;
  float s = 0.f, sq = 0.f;
  for (int b = 0; b < BATCH; ++b) {
    const float* yr = y + ((size_t)b * CH + c) * NS;
    for (int n = tid; n < NS; n += 256) {
      float v = yr[n];
      s += v;
      sq += v * v;
    }
  }
  __shared__ float rs[256];
  __shared__ float rq[256];
  rs[tid] = s;
  rq[tid] = sq;
  __syncthreads();
  for (int st = 128; st > 0; st >>= 1) {
    if (tid < st) {
      rs[tid] += rs[tid + st];
      rq[tid] += rq[tid + st];
    }
    __syncthreads();
  }
  if (tid == 0) {
    const float inv = 1.f / (BATCH * NS);
    float mean = rs[0] * inv;
    float var = rq[0] * inv - mean * mean;
    if (var < 0.f) var = 0.f;
    float r = rsqrtf(var + EPSF);
    float sc = gamma[c] * r;
    scale[c] = sc;
    shift[c] = beta[c] - mean * sc;
  }
}

// ---------------------------------------------------------------------------
// 5. f[b][c] = max_n relu(scale*y3+shift)   (relu(max) == max(relu))
// ---------------------------------------------------------------------------
__global__ __launch_bounds__(256) void k_max(const float* __restrict__ y,
                                             const float* __restrict__ scale,
                                             const float* __restrict__ shift,
                                             float* __restrict__ f) {
  int idx = blockIdx.x;  // b*CH + c
  int c = idx & (CH - 1);
  const float* yr = y + (size_t)idx * NS;
  float sc = scale[c], sh = shift[c];
  float m = -1e30f;
  for (int n = threadIdx.x; n < NS; n += 256) m = fmaxf(m, sc * yr[n] + sh);
#pragma unroll
  for (int o = 32; o > 0; o >>= 1) m = fmaxf(m, __shfl_down(m, o, 64));
  __shared__ float wm[4];
  if ((threadIdx.x & 63) == 0) wm[threadIdx.x >> 6] = m;
  __syncthreads();
  if (threadIdx.x == 0) {
    m = fmaxf(fmaxf(wm[0], wm[1]), fmaxf(wm[2], wm[3]));
    f[idx] = fmaxf(m, 0.f);
  }
}

// ---------------------------------------------------------------------------
// 6. Head MLP: (8,128) -> fc+bn1+relu -> fc+bn1+relu -> fc(12); one block
// ---------------------------------------------------------------------------
__global__ __launch_bounds__(128) void k_head(const float* __restrict__ f,
                                              const float* __restrict__ hw1, const float* __restrict__ hb1,
                                              const float* __restrict__ hg1, const float* __restrict__ hbe1,
                                              const float* __restrict__ hw2, const float* __restrict__ hb2,
                                              const float* __restrict__ hg2, const float* __restrict__ hbe2,
                                              const float* __restrict__ hw3, const float* __restrict__ hb3,
                                              const float* __restrict__ center,
                                              float* __restrict__ out) {
  __shared__ float A[BATCH * 128];
  __shared__ float Bm[BATCH * 128];
  int c = threadIdx.x;
  for (int b = 0; b < BATCH; ++b) A[b * 128 + c] = f[b * 128 + c];
  __syncthreads();

  // layer h1: read A, write Bm
  {
    float v[BATCH];
    float bs = hb1[c];
#pragma unroll
    for (int b = 0; b < BATCH; ++b) v[b] = bs;
    for (int k = 0; k < 128; ++k) {
      float w = hw1[c * 128 + k];
#pragma unroll
      for (int b = 0; b < BATCH; ++b) v[b] += A[b * 128 + k] * w;
    }
    float m = 0.f;
#pragma unroll
    for (int b = 0; b < BATCH; ++b) m += v[b];
    m *= (1.f / BATCH);
    float var = 0.f;
#pragma unroll
    for (int b = 0; b < BATCH; ++b) { float d = v[b] - m; var += d * d; }
    var *= (1.f / BATCH);
    float r = rsqrtf(var + EPSF);
    float ga = hg1[c], be = hbe1[c];
#pragma unroll
    for (int b = 0; b < BATCH; ++b)
      Bm[b * 128 + c] = fmaxf(ga * (v[b] - m) * r + be, 0.f);
  }
  __syncthreads();

  // layer h2: read Bm, write A
  {
    float v[BATCH];
    float bs = hb2[c];
#pragma unroll
    for (int b = 0; b < BATCH; ++b) v[b] = bs;
    for (int k = 0; k < 128; ++k) {
      float w = hw2[c * 128 + k];
#pragma unroll
      for (int b = 0; b < BATCH; ++b) v[b] += Bm[b * 128 + k] * w;
    }
    float m = 0.f;
#pragma unroll
    for (int b = 0; b < BATCH; ++b) m += v[b];
    m *= (1.f / BATCH);
    float var = 0.f;
#pragma unroll
    for (int b = 0; b < BATCH; ++b) { float d = v[b] - m; var += d * d; }
    var *= (1.f / BATCH);
    float r = rsqrtf(var + EPSF);
    float ga = hg2[c], be = hbe2[c];
#pragma unroll
    for (int b = 0; b < BATCH; ++b)
      A[b * 128 + c] = fmaxf(ga * (v[b] - m) * r + be, 0.f);
  }
  __syncthreads();

  // layer h3: 12 outputs x 8 batches = 96 threads
  if (c < 96) {
    int b = c / 12, j = c % 12;
    float o = hb3[j];
    for (int k = 0; k < 128; ++k) o += A[b * 128 + k] * hw3[j * 128 + k];
    if (j < 3)      out[b * 3 + j] = center[b * 3 + j] + o;
    else if (j < 6) out[24 + b * 3 + (j - 3)] = o;
    else            out[48 + b * 6 + (j - 6)] = o;
  }
}

// ---------------------------------------------------------------------------
extern "C" void kernel_launch(void* const* d_in, const int* in_sizes, int n_in,
                              void* d_out, int out_size, void* d_ws, size_t ws_size,
                              hipStream_t stream) {
  const float* xyz  = (const float*)d_in[0];
  const float* feat = (const float*)d_in[1];
  const float* w1   = (const float*)d_in[2];
  const float* b1   = (const float*)d_in[3];
  const float* ga1  = (const float*)d_in[4];
  const float* be1  = (const float*)d_in[5];
  const float* w2   = (const float*)d_in[6];
  const float* b2   = (const float*)d_in[7];
  const float* ga2  = (const float*)d_in[8];
  const float* be2  = (const float*)d_in[9];
  const float* w3   = (const float*)d_in[10];
  const float* b3   = (const float*)d_in[11];
  const float* ga3  = (const float*)d_in[12];
  const float* be3  = (const float*)d_in[13];
  const float* hw1  = (const float*)d_in[14];
  const float* hb1  = (const float*)d_in[15];
  const float* hg1  = (const float*)d_in[16];
  const float* hbe1 = (const float*)d_in[17];
  const float* hw2  = (const float*)d_in[18];
  const float* hb2  = (const float*)d_in[19];
  const float* hg2  = (const float*)d_in[20];
  const float* hbe2 = (const float*)d_in[21];
  const float* hw3  = (const float*)d_in[22];
  const float* hb3  = (const float*)d_in[23];
  float* out = (float*)d_out;

  char* ws = (char*)d_ws;
  size_t off = 0;
  auto alloc = [&](size_t bytes) -> void* {
    void* p = ws + off;
    off = (off + bytes + 255) & ~(size_t)255;
    return p;
  };
  // live ranges: g dead after gemm1 -> y2 aliases g; y1 dead after gemm2 -> y3 aliases y1
  int*   inds   = (int*)alloc((size_t)BATCH * NS * 4);
  float* center = (float*)alloc(BATCH * 3 * 4);
  float* sc1    = (float*)alloc(CH * 4);
  float* sh1    = (float*)alloc(CH * 4);
  float* sc2    = (float*)alloc(CH * 4);
  float* sh2    = (float*)alloc(CH * 4);
  float* sc3    = (float*)alloc(CH * 4);
  float* sh3    = (float*)alloc(CH * 4);
  float* fmaxb  = (float*)alloc(BATCH * CH * 4);
  float* g      = (float*)alloc((size_t)BATCH * K1 * NS * 4);  // 8.5 MB
  float* y1     = (float*)alloc((size_t)BATCH * CH * NS * 4);  // 4.2 MB
  float* y2     = g;   // alias: g dead once gemm1 has run
  float* y3     = y1;  // alias: y1 dead once gemm2 has run

  k_select<<<dim3(BATCH), dim3(1024), 0, stream>>>(xyz, inds, center);
  k_gather<<<dim3(BATCH * K1), dim3(256), 0, stream>>>(xyz, feat, inds, center, g);
  k_gemm1<<<dim3(NS / 64, BATCH), dim3(256), 0, stream>>>(g, w1, b1, y1);
  k_stats<<<dim3(CH), dim3(256), 0, stream>>>(y1, ga1, be1, sc1, sh1);
  k_gemm23<<<dim3(NS / 64, BATCH), dim3(256), 0, stream>>>(y1, sc1, sh1, w2, b2, y2);
  k_stats<<<dim3(CH), dim3(256), 0, stream>>>(y2, ga2, be2, sc2, sh2);
  k_gemm23<<<dim3(NS / 64, BATCH), dim3(256), 0, stream>>>(y2, sc2, sh2, w3, b3, y3);
  k_stats<<<dim3(CH), dim3(256), 0, stream>>>(y3, ga3, be3, sc3, sh3);
  k_max<<<dim3(BATCH * CH), dim3(256), 0, stream>>>(y3, sc3, sh3, fmaxb);
  k_head<<<dim3(1), dim3(128), 0, stream>>>(fmaxb, hw1, hb1, hg1, hbe1,
                                            hw2, hb2, hg2, hbe2, hw3, hb3,
                                            center, out);
}

// Round 3
// 848.967 us; speedup vs baseline: 1.0418x; 1.0418x over previous
//
#include <hip/hip_runtime.h>
#include <hip/hip_bf16.h>
#include <stdint.h>

#define BATCH 8
#define NPTS  65536
#define CFEAT 256
#define K1    259     // 3 + 256
#define CH    128
#define NS    1024
#define EPSF  1e-5f
#define INVN  (1.0f / (BATCH * NS))

// ---------------------------------------------------------------------------
// 1. Selection: per batch, first NS masked indices in ascending order (fill 0)
// ---------------------------------------------------------------------------
__global__ __launch_bounds__(1024) void k_select(const float* __restrict__ xyz,
                                                 int* __restrict__ inds,
                                                 float* __restrict__ center) {
  int b = blockIdx.x;
  int tid = threadIdx.x;
  int lane = tid & 63, wid = tid >> 6;
  const float* xb = xyz + (size_t)b * NPTS * 3;
  float cx = xb[0], cy = xb[1], cz = xb[2];
  if (tid < 3) center[b * 3 + tid] = xb[tid];

  __shared__ int wcnt[16];
  int total = 0;
  int* ib = inds + b * NS;

  for (int base = 0; base < NPTS; base += 1024) {
    int i = base + tid;
    float dx = xb[(size_t)i * 3 + 0] - cx;
    float dy = xb[(size_t)i * 3 + 1] - cy;
    float dz = xb[(size_t)i * 3 + 2] - cz;
    float d2 = dx * dx + dy * dy + dz * dz;
    bool pred = d2 < 1.0f;
    unsigned long long bal = __ballot(pred);
    if (lane == 0) wcnt[wid] = (int)__popcll(bal);
    __syncthreads();
    int woff = 0, itot = 0;
#pragma unroll
    for (int w = 0; w < 16; ++w) {
      int c = wcnt[w];
      if (w < wid) woff += c;
      itot += c;
    }
    int pos = total + woff + (int)__popcll(bal & ((1ull << lane) - 1ull));
    if (pred && pos < NS) ib[pos] = i;
    total += itot;
    __syncthreads();
    if (total >= NS) break;
  }
  for (int j = total + tid; j < NS; j += 1024) ib[j] = 0;
}

// ---------------------------------------------------------------------------
// Shared epilogue helper: store + per-channel partial BN stats via atomics
// ---------------------------------------------------------------------------
__device__ __forceinline__ void store_and_stats(float* __restrict__ yb,
                                                float* __restrict__ sums,
                                                const float* __restrict__ bias,
                                                float acc[4][4],
                                                int n0, int tx, int ty) {
#pragma unroll
  for (int r = 0; r < 4; ++r) {
    int o = ty * 4 + r;
    float bs = bias[o];
    float4 v = make_float4(acc[r][0] + bs, acc[r][1] + bs,
                           acc[r][2] + bs, acc[r][3] + bs);
    *(float4*)&yb[(size_t)o * NS + n0 + tx * 4] = v;
    float s = v.x + v.y + v.z + v.w;
    float q = v.x * v.x + v.y * v.y + v.z * v.z + v.w * v.w;
    s += __shfl_xor(s, 1, 64); q += __shfl_xor(q, 1, 64);
    s += __shfl_xor(s, 2, 64); q += __shfl_xor(q, 2, 64);
    s += __shfl_xor(s, 4, 64); q += __shfl_xor(q, 4, 64);
    if (tx == 0) {
      atomicAdd(&sums[o], s);
      atomicAdd(&sums[CH + o], q);
    }
  }
}

// ---------------------------------------------------------------------------
// 2. GEMM layer 1 with gather fused into X staging.  Tile: 128 rows x 32 cols.
//    Ws LDS layout [kk][o] (pad 132), Xs [kk][j] (pad 36) -> b128 reads, no
//    bank conflicts on the read side.
// ---------------------------------------------------------------------------
__global__ __launch_bounds__(256) void k_gemm1(const float* __restrict__ xyz,
                                               const float* __restrict__ feat,
                                               const int* __restrict__ inds,
                                               const float* __restrict__ center,
                                               const float* __restrict__ W,
                                               const float* __restrict__ bias,
                                               float* __restrict__ y,
                                               float* __restrict__ sums) {
  __shared__ float Ws[32][132];
  __shared__ float Xs[32][36];
  __shared__ int   ids[32];
  __shared__ float cenl[3];
  int b = blockIdx.y;
  int n0 = blockIdx.x * 32;
  int tid = threadIdx.x;
  if (tid < 32) ids[tid] = inds[b * NS + n0 + tid];
  if (tid < 3)  cenl[tid] = center[b * 3 + tid];
  __syncthreads();

  int tx = tid & 7, ty = tid >> 3;   // cols tx*4..+3, rows ty*4..+3
  float acc[4][4];
#pragma unroll
  for (int r = 0; r < 4; ++r)
#pragma unroll
    for (int j = 0; j < 4; ++j) acc[r][j] = 0.f;

  const float* featb = feat + (size_t)b * CFEAT * NPTS;
  const float* xyzb  = xyz + (size_t)b * NPTS * 3;

  for (int k0 = 0; k0 < K1; k0 += 32) {
    // Ws: 128x32 chunk, coalesced global read (k fast), transposed LDS write
#pragma unroll
    for (int i = 0; i < 16; ++i) {
      int e = tid + 256 * i;
      int o = e >> 5, kk = e & 31;
      int k = k0 + kk;
      Ws[kk][o] = (k < K1) ? W[o * K1 + k] : 0.f;
    }
    // Xs: gather 32 channels x 32 points
#pragma unroll
    for (int i = 0; i < 4; ++i) {
      int e = tid + 256 * i;
      int kk = e >> 5, j = e & 31;
      int k = k0 + kk;
      float v = 0.f;
      int id = ids[j];
      if (k < 3)        v = xyzb[(size_t)id * 3 + k] - cenl[k];
      else if (k < K1)  v = featb[(size_t)(k - 3) * NPTS + id];
      Xs[kk][j] = v;
    }
    __syncthreads();
#pragma unroll
    for (int kk = 0; kk < 32; ++kk) {
      float4 xv = *(const float4*)&Xs[kk][tx * 4];
      float4 wv = *(const float4*)&Ws[kk][ty * 4];
      acc[0][0] += wv.x * xv.x; acc[0][1] += wv.x * xv.y; acc[0][2] += wv.x * xv.z; acc[0][3] += wv.x * xv.w;
      acc[1][0] += wv.y * xv.x; acc[1][1] += wv.y * xv.y; acc[1][2] += wv.y * xv.z; acc[1][3] += wv.y * xv.w;
      acc[2][0] += wv.z * xv.x; acc[2][1] += wv.z * xv.y; acc[2][2] += wv.z * xv.z; acc[2][3] += wv.z * xv.w;
      acc[3][0] += wv.w * xv.x; acc[3][1] += wv.w * xv.y; acc[3][2] += wv.w * xv.z; acc[3][3] += wv.w * xv.w;
    }
    __syncthreads();
  }
  store_and_stats(y + (size_t)b * CH * NS, sums, bias, acc, n0, tx, ty);
}

// ---------------------------------------------------------------------------
// 3. GEMM layers 2/3 (K=128). BN+ReLU of the previous layer applied during
//    X staging using sums accumulated by the producer kernel.
// ---------------------------------------------------------------------------
__global__ __launch_bounds__(256) void k_gemm23(const float* __restrict__ x,
                                                const float* __restrict__ sums_prev,
                                                const float* __restrict__ gamma,
                                                const float* __restrict__ beta,
                                                const float* __restrict__ W,
                                                const float* __restrict__ bias,
                                                float* __restrict__ y,
                                                float* __restrict__ sums_out) {
  __shared__ float Ws[32][132];
  __shared__ float Xs[32][36];
  __shared__ float scl[CH], shf[CH];
  int b = blockIdx.y;
  int n0 = blockIdx.x * 32;
  int tid = threadIdx.x;
  if (tid < CH) {
    float s = sums_prev[tid], q = sums_prev[CH + tid];
    float mean = s * INVN;
    float var = fmaxf(q * INVN - mean * mean, 0.f);
    float sc = gamma[tid] * rsqrtf(var + EPSF);
    scl[tid] = sc;
    shf[tid] = beta[tid] - mean * sc;
  }
  __syncthreads();

  int tx = tid & 7, ty = tid >> 3;
  float acc[4][4];
#pragma unroll
  for (int r = 0; r < 4; ++r)
#pragma unroll
    for (int j = 0; j < 4; ++j) acc[r][j] = 0.f;

  const float* xb = x + (size_t)b * CH * NS;

  for (int k0 = 0; k0 < CH; k0 += 32) {
#pragma unroll
    for (int i = 0; i < 16; ++i) {
      int e = tid + 256 * i;
      int o = e >> 5, kk = e & 31;
      Ws[kk][o] = W[o * CH + k0 + kk];
    }
#pragma unroll
    for (int i = 0; i < 4; ++i) {
      int e = tid + 256 * i;
      int kk = e >> 5, j = e & 31;
      int k = k0 + kk;
      float v = xb[(size_t)k * NS + n0 + j];
      Xs[kk][j] = fmaxf(scl[k] * v + shf[k], 0.f);
    }
    __syncthreads();
#pragma unroll
    for (int kk = 0; kk < 32; ++kk) {
      float4 xv = *(const float4*)&Xs[kk][tx * 4];
      float4 wv = *(const float4*)&Ws[kk][ty * 4];
      acc[0][0] += wv.x * xv.x; acc[0][1] += wv.x * xv.y; acc[0][2] += wv.x * xv.z; acc[0][3] += wv.x * xv.w;
      acc[1][0] += wv.y * xv.x; acc[1][1] += wv.y * xv.y; acc[1][2] += wv.y * xv.z; acc[1][3] += wv.y * xv.w;
      acc[2][0] += wv.z * xv.x; acc[2][1] += wv.z * xv.y; acc[2][2] += wv.z * xv.z; acc[2][3] += wv.z * xv.w;
      acc[3][0] += wv.w * xv.x; acc[3][1] += wv.w * xv.y; acc[3][2] += wv.w * xv.z; acc[3][3] += wv.w * xv.w;
    }
    __syncthreads();
  }
  store_and_stats(y + (size_t)b * CH * NS, sums_out, bias, acc, n0, tx, ty);
}

// ---------------------------------------------------------------------------
// 4. f[b][c] = max_n relu(bn(y3)) ; scale/shift computed inline from sums3
// ---------------------------------------------------------------------------
__global__ __launch_bounds__(256) void k_max(const float* __restrict__ y,
                                             const float* __restrict__ sums,
                                             const float* __restrict__ gamma,
                                             const float* __restrict__ beta,
                                             float* __restrict__ f) {
  int idx = blockIdx.x;  // b*CH + c
  int c = idx & (CH - 1);
  float s = sums[c], q = sums[CH + c];
  float mean = s * INVN;
  float var = fmaxf(q * INVN - mean * mean, 0.f);
  float sc = gamma[c] * rsqrtf(var + EPSF);
  float sh = beta[c] - mean * sc;
  const float* yr = y + (size_t)idx * NS;
  float m = -1e30f;
  for (int n = threadIdx.x; n < NS; n += 256) m = fmaxf(m, sc * yr[n] + sh);
#pragma unroll
  for (int o = 32; o > 0; o >>= 1) m = fmaxf(m, __shfl_down(m, o, 64));
  __shared__ float wm[4];
  if ((threadIdx.x & 63) == 0) wm[threadIdx.x >> 6] = m;
  __syncthreads();
  if (threadIdx.x == 0) {
    m = fmaxf(fmaxf(wm[0], wm[1]), fmaxf(wm[2], wm[3]));
    f[idx] = fmaxf(m, 0.f);
  }
}

// ---------------------------------------------------------------------------
// 5. Head MLP: (8,128) -> fc+bn1+relu -> fc+bn1+relu -> fc(12); one block
// ---------------------------------------------------------------------------
__global__ __launch_bounds__(128) void k_head(const float* __restrict__ f,
                                              const float* __restrict__ hw1, const float* __restrict__ hb1,
                                              const float* __restrict__ hg1, const float* __restrict__ hbe1,
                                              const float* __restrict__ hw2, const float* __restrict__ hb2,
                                              const float* __restrict__ hg2, const float* __restrict__ hbe2,
                                              const float* __restrict__ hw3, const float* __restrict__ hb3,
                                              const float* __restrict__ center,
                                              float* __restrict__ out) {
  __shared__ float A[BATCH * 128];
  __shared__ float Bm[BATCH * 128];
  int c = threadIdx.x;
  for (int b = 0; b < BATCH; ++b) A[b * 128 + c] = f[b * 128 + c];
  __syncthreads();

  {
    float v[BATCH];
    float bs = hb1[c];
#pragma unroll
    for (int b = 0; b < BATCH; ++b) v[b] = bs;
    const float4* w4 = (const float4*)hw1 + c * 32;
    for (int k4 = 0; k4 < 32; ++k4) {
      float4 w = w4[k4];
#pragma unroll
      for (int b = 0; b < BATCH; ++b) {
        const float* Ar = &A[b * 128 + k4 * 4];
        v[b] += Ar[0] * w.x + Ar[1] * w.y + Ar[2] * w.z + Ar[3] * w.w;
      }
    }
    float m = 0.f;
#pragma unroll
    for (int b = 0; b < BATCH; ++b) m += v[b];
    m *= (1.f / BATCH);
    float var = 0.f;
#pragma unroll
    for (int b = 0; b < BATCH; ++b) { float d = v[b] - m; var += d * d; }
    var *= (1.f / BATCH);
    float r = rsqrtf(var + EPSF);
    float ga = hg1[c], be = hbe1[c];
#pragma unroll
    for (int b = 0; b < BATCH; ++b)
      Bm[b * 128 + c] = fmaxf(ga * (v[b] - m) * r + be, 0.f);
  }
  __syncthreads();

  {
    float v[BATCH];
    float bs = hb2[c];
#pragma unroll
    for (int b = 0; b < BATCH; ++b) v[b] = bs;
    const float4* w4 = (const float4*)hw2 + c * 32;
    for (int k4 = 0; k4 < 32; ++k4) {
      float4 w = w4[k4];
#pragma unroll
      for (int b = 0; b < BATCH; ++b) {
        const float* Br = &Bm[b * 128 + k4 * 4];
        v[b] += Br[0] * w.x + Br[1] * w.y + Br[2] * w.z + Br[3] * w.w;
      }
    }
    float m = 0.f;
#pragma unroll
    for (int b = 0; b < BATCH; ++b) m += v[b];
    m *= (1.f / BATCH);
    float var = 0.f;
#pragma unroll
    for (int b = 0; b < BATCH; ++b) { float d = v[b] - m; var += d * d; }
    var *= (1.f / BATCH);
    float r = rsqrtf(var + EPSF);
    float ga = hg2[c], be = hbe2[c];
#pragma unroll
    for (int b = 0; b < BATCH; ++b)
      A[b * 128 + c] = fmaxf(ga * (v[b] - m) * r + be, 0.f);
  }
  __syncthreads();

  if (c < 96) {
    int b = c / 12, j = c % 12;
    float o = hb3[j];
    const float4* w4 = (const float4*)hw3 + j * 32;
    for (int k4 = 0; k4 < 32; ++k4) {
      float4 w = w4[k4];
      const float* Ar = &A[b * 128 + k4 * 4];
      o += Ar[0] * w.x + Ar[1] * w.y + Ar[2] * w.z + Ar[3] * w.w;
    }
    if (j < 3)      out[b * 3 + j] = center[b * 3 + j] + o;
    else if (j < 6) out[24 + b * 3 + (j - 3)] = o;
    else            out[48 + b * 6 + (j - 6)] = o;
  }
}

// ---------------------------------------------------------------------------
extern "C" void kernel_launch(void* const* d_in, const int* in_sizes, int n_in,
                              void* d_out, int out_size, void* d_ws, size_t ws_size,
                              hipStream_t stream) {
  const float* xyz  = (const float*)d_in[0];
  const float* feat = (const float*)d_in[1];
  const float* w1   = (const float*)d_in[2];
  const float* b1   = (const float*)d_in[3];
  const float* ga1  = (const float*)d_in[4];
  const float* be1  = (const float*)d_in[5];
  const float* w2   = (const float*)d_in[6];
  const float* b2   = (const float*)d_in[7];
  const float* ga2  = (const float*)d_in[8];
  const float* be2  = (const float*)d_in[9];
  const float* w3   = (const float*)d_in[10];
  const float* b3   = (const float*)d_in[11];
  const float* ga3  = (const float*)d_in[12];
  const float* be3  = (const float*)d_in[13];
  const float* hw1  = (const float*)d_in[14];
  const float* hb1  = (const float*)d_in[15];
  const float* hg1  = (const float*)d_in[16];
  const float* hbe1 = (const float*)d_in[17];
  const float* hw2  = (const float*)d_in[18];
  const float* hb2  = (const float*)d_in[19];
  const float* hg2  = (const float*)d_in[20];
  const float* hbe2 = (const float*)d_in[21];
  const float* hw3  = (const float*)d_in[22];
  const float* hb3  = (const float*)d_in[23];
  float* out = (float*)d_out;

  char* ws = (char*)d_ws;
  size_t off = 0;
  auto alloc = [&](size_t bytes) -> void* {
    void* p = ws + off;
    off = (off + bytes + 255) & ~(size_t)255;
    return p;
  };
  // sums first (contiguous, one small memset covers all three)
  float* sums1  = (float*)alloc(2 * CH * 4);
  float* sums2  = (float*)alloc(2 * CH * 4);
  float* sums3  = (float*)alloc(2 * CH * 4);
  int*   inds   = (int*)alloc((size_t)BATCH * NS * 4);
  float* center = (float*)alloc(BATCH * 3 * 4);
  float* fmaxb  = (float*)alloc(BATCH * CH * 4);
  float* y1     = (float*)alloc((size_t)BATCH * CH * NS * 4);  // 4.2 MB
  float* y2     = (float*)alloc((size_t)BATCH * CH * NS * 4);  // 4.2 MB
  float* y3     = y1;  // alias: y1 dead once gemm2 consumed it

  hipMemsetAsync(sums1, 0, ((char*)center - (char*)sums1), stream);

  k_select<<<dim3(BATCH), dim3(1024), 0, stream>>>(xyz, inds, center);
  k_gemm1<<<dim3(NS / 32, BATCH), dim3(256), 0, stream>>>(xyz, feat, inds, center,
                                                          w1, b1, y1, sums1);
  k_gemm23<<<dim3(NS / 32, BATCH), dim3(256), 0, stream>>>(y1, sums1, ga1, be1,
                                                           w2, b2, y2, sums2);
  k_gemm23<<<dim3(NS / 32, BATCH), dim3(256), 0, stream>>>(y2, sums2, ga2, be2,
                                                           w3, b3, y3, sums3);
  k_max<<<dim3(BATCH * CH), dim3(256), 0, stream>>>(y3, sums3, ga3, be3, fmaxb);
  k_head<<<dim3(1), dim3(128), 0, stream>>>(fmaxb, hw1, hb1, hg1, hbe1,
                                            hw2, hb2, hg2, hbe2, hw3, hb3,
                                            center, out);
}